// Round 1
// baseline (264.039 us; speedup 1.0000x reference)
//
#include <hip/hip_runtime.h>
#include <stdint.h>

#define NBINS 2048
#define CAND_CAP 32768
#define NBLOCKS 512
#define NTHREADS 1024

// ws layout (unsigned ints):
// [0, 2048)        : coarse histogram (top 11 bits of abs bits)
// [2048]           : candidate counter
// [2049]           : minkey (ordered-uint encoding of global min)
// [2050], [2051]   : selected bucket b, residual rank r (1-indexed)
// [2064, 2064+CAND_CAP) : candidate abs-bit patterns

__device__ __forceinline__ unsigned fkey(float f) {
    unsigned u = __float_as_uint(f);
    return (u & 0x80000000u) ? ~u : (u | 0x80000000u);
}

__global__ __launch_bounds__(NTHREADS) void histmin_kernel(
    const float* __restrict__ in, long long n,
    unsigned* __restrict__ hist, unsigned* __restrict__ minkey) {
    __shared__ unsigned h[NBINS];
    for (int i = threadIdx.x; i < NBINS; i += blockDim.x) h[i] = 0;
    __syncthreads();

    long long tid = (long long)blockIdx.x * blockDim.x + threadIdx.x;
    long long stride = (long long)gridDim.x * blockDim.x;
    const float4* in4 = (const float4*)in;
    long long n4 = n >> 2;

    float mn = 3.402823466e+38f;
    for (long long i = tid; i < n4; i += stride) {
        float4 v = in4[i];
        mn = fminf(mn, fminf(fminf(v.x, v.y), fminf(v.z, v.w)));
        unsigned ux = __float_as_uint(v.x) & 0x7FFFFFFFu;
        unsigned uy = __float_as_uint(v.y) & 0x7FFFFFFFu;
        unsigned uz = __float_as_uint(v.z) & 0x7FFFFFFFu;
        unsigned uw = __float_as_uint(v.w) & 0x7FFFFFFFu;
        atomicAdd(&h[ux >> 20], 1u);
        atomicAdd(&h[uy >> 20], 1u);
        atomicAdd(&h[uz >> 20], 1u);
        atomicAdd(&h[uw >> 20], 1u);
    }
    // tail (n not multiple of 4)
    for (long long i = (n4 << 2) + tid; i < n; i += stride) {
        float v = in[i];
        mn = fminf(mn, v);
        atomicAdd(&h[(__float_as_uint(v) & 0x7FFFFFFFu) >> 20], 1u);
    }
    __syncthreads();

    // flush histogram
    for (int i = threadIdx.x; i < NBINS; i += blockDim.x) {
        unsigned c = h[i];
        if (c) atomicAdd(&hist[i], c);
    }

    // block min reduce
    unsigned key = fkey(mn);
    for (int off = 32; off > 0; off >>= 1)
        key = min(key, (unsigned)__shfl_down((int)key, off));
    __shared__ unsigned wmin[NTHREADS / 64];
    if ((threadIdx.x & 63) == 0) wmin[threadIdx.x >> 6] = key;
    __syncthreads();
    if (threadIdx.x == 0) {
        unsigned m = wmin[0];
        for (int w = 1; w < (int)(blockDim.x >> 6); ++w) m = min(m, wmin[w]);
        atomicMin(minkey, m);
    }
}

__global__ void select_bucket_kernel(const unsigned* __restrict__ hist,
                                     unsigned k, unsigned* __restrict__ sel) {
    __shared__ unsigned part[256];
    int t = threadIdx.x;  // 256 threads
    unsigned s = 0;
    for (int j = 0; j < 8; ++j) s += hist[t * 8 + j];
    part[t] = s;
    __syncthreads();
    if (t == 0) {
        unsigned cum = 0;
        int seg = 0;
        for (; seg < 256; ++seg) {
            if (cum + part[seg] >= k) break;
            cum += part[seg];
        }
        int b = seg * 8;
        for (;; ++b) {
            unsigned c = hist[b];
            if (cum + c >= k) break;
            cum += c;
        }
        sel[0] = (unsigned)b;
        sel[1] = k - cum;  // 1-indexed rank within bucket
    }
}

__global__ __launch_bounds__(NTHREADS) void compact_kernel(
    const float* __restrict__ in, long long n,
    const unsigned* __restrict__ sel, unsigned* __restrict__ counter,
    unsigned* __restrict__ cand) {
    unsigned b = sel[0];
    long long tid = (long long)blockIdx.x * blockDim.x + threadIdx.x;
    long long stride = (long long)gridDim.x * blockDim.x;
    const float4* in4 = (const float4*)in;
    long long n4 = n >> 2;
    for (long long i = tid; i < n4; i += stride) {
        float4 v = in4[i];
        unsigned u[4];
        u[0] = __float_as_uint(v.x) & 0x7FFFFFFFu;
        u[1] = __float_as_uint(v.y) & 0x7FFFFFFFu;
        u[2] = __float_as_uint(v.z) & 0x7FFFFFFFu;
        u[3] = __float_as_uint(v.w) & 0x7FFFFFFFu;
#pragma unroll
        for (int j = 0; j < 4; ++j) {
            if ((u[j] >> 20) == b) {
                unsigned p = atomicAdd(counter, 1u);
                if (p < CAND_CAP) cand[p] = u[j];
            }
        }
    }
    for (long long i = (n4 << 2) + tid; i < n; i += stride) {
        unsigned u = __float_as_uint(in[i]) & 0x7FFFFFFFu;
        if ((u >> 20) == b) {
            unsigned p = atomicAdd(counter, 1u);
            if (p < CAND_CAP) cand[p] = u;
        }
    }
}

__global__ __launch_bounds__(1024) void final_kernel(
    const unsigned* __restrict__ cand, const unsigned* __restrict__ counterp,
    const unsigned* __restrict__ sel, const unsigned* __restrict__ minkeyp,
    const float* __restrict__ min_val, const float* __restrict__ max_val,
    const int* __restrict__ num_flag, float* __restrict__ out) {
    __shared__ unsigned h[1024];
    __shared__ unsigned part[32];
    __shared__ unsigned bsel[2];

    unsigned m = min(*counterp, (unsigned)CAND_CAP);
    unsigned b = sel[0];
    unsigned r = sel[1];

    // level 1: bits 19..10
    h[threadIdx.x] = 0;
    __syncthreads();
    for (unsigned i = threadIdx.x; i < m; i += blockDim.x)
        atomicAdd(&h[(cand[i] >> 10) & 1023u], 1u);
    __syncthreads();
    if (threadIdx.x < 32) {
        unsigned s = 0;
        for (int j = 0; j < 32; ++j) s += h[threadIdx.x * 32 + j];
        part[threadIdx.x] = s;
    }
    __syncthreads();
    if (threadIdx.x == 0) {
        unsigned cum = 0;
        int seg = 0;
        for (; seg < 32; ++seg) {
            if (cum + part[seg] >= r) break;
            cum += part[seg];
        }
        int i = seg * 32;
        for (;; ++i) {
            if (cum + h[i] >= r) break;
            cum += h[i];
        }
        bsel[0] = (unsigned)i;
        bsel[1] = r - cum;
    }
    __syncthreads();
    unsigned b1 = bsel[0];
    r = bsel[1];

    // level 2: bits 9..0
    h[threadIdx.x] = 0;
    __syncthreads();
    for (unsigned i = threadIdx.x; i < m; i += blockDim.x) {
        unsigned u = cand[i];
        if (((u >> 10) & 1023u) == b1) atomicAdd(&h[u & 1023u], 1u);
    }
    __syncthreads();
    if (threadIdx.x < 32) {
        unsigned s = 0;
        for (int j = 0; j < 32; ++j) s += h[threadIdx.x * 32 + j];
        part[threadIdx.x] = s;
    }
    __syncthreads();
    if (threadIdx.x == 0) {
        unsigned cum = 0;
        int seg = 0;
        for (; seg < 32; ++seg) {
            if (cum + part[seg] >= r) break;
            cum += part[seg];
        }
        int i = seg * 32;
        for (;; ++i) {
            if (cum + h[i] >= r) break;
            cum += h[i];
        }
        unsigned bits = (b << 20) | (b1 << 10) | (unsigned)i;
        float maxcur = __uint_as_float(bits);
        unsigned mk = *minkeyp;
        float mincur = (mk & 0x80000000u) ? __uint_as_float(mk & 0x7FFFFFFFu)
                                          : __uint_as_float(~mk);
        bool first = (*num_flag == 0);
        float nmax = first ? maxcur : (0.9f * max_val[0] + 0.1f * maxcur);
        float nmin = first ? mincur : (0.9f * min_val[0] + 0.1f * mincur);
        out[0] = nmin;
        out[1] = nmax;
    }
}

extern "C" void kernel_launch(void* const* d_in, const int* in_sizes, int n_in,
                              void* d_out, int out_size, void* d_ws, size_t ws_size,
                              hipStream_t stream) {
    const float* in = (const float*)d_in[0];
    const float* minv = (const float*)d_in[1];
    const float* maxv = (const float*)d_in[2];
    const int* flag = (const int*)d_in[3];
    float* out = (float*)d_out;

    long long n = (long long)in_sizes[0];
    // k = int(0.9999 * n), matching Python's double arithmetic + truncation
    unsigned k = (unsigned)(long long)(0.9999 * (double)n);

    unsigned* ws = (unsigned*)d_ws;
    unsigned* hist = ws;            // 2048
    unsigned* counter = ws + 2048;  // 1
    unsigned* minkey = ws + 2049;   // 1
    unsigned* sel = ws + 2050;      // 2
    unsigned* cand = ws + 2064;     // CAND_CAP

    hipMemsetAsync(ws, 0, 2064 * sizeof(unsigned), stream);
    hipMemsetAsync(minkey, 0xFF, sizeof(unsigned), stream);

    histmin_kernel<<<NBLOCKS, NTHREADS, 0, stream>>>(in, n, hist, minkey);
    select_bucket_kernel<<<1, 256, 0, stream>>>(hist, k, sel);
    compact_kernel<<<NBLOCKS, NTHREADS, 0, stream>>>(in, n, sel, counter, cand);
    final_kernel<<<1, 1024, 0, stream>>>(cand, counter, sel, minkey,
                                         minv, maxv, flag, out);
}

// Round 2
// 262.420 us; speedup vs baseline: 1.0062x; 1.0062x over previous
//
#include <hip/hip_runtime.h>
#include <stdint.h>

#define NBINS 2048
#define NC 8            // histogram copies, bin-interleaved
#define CAND_CAP 32768
#define NBLOCKS 512
#define NTHREADS 1024

// ws layout (unsigned ints):
// [0, 2048)        : coarse histogram (top 11 bits of abs bits)
// [2048]           : candidate counter
// [2049]           : minkey (ordered-uint encoding of global min)
// [2050], [2051]   : selected bucket b, residual rank r (1-indexed)
// [2064, 2064+CAND_CAP) : candidate abs-bit patterns

__device__ __forceinline__ unsigned fkey(float f) {
    unsigned u = __float_as_uint(f);
    return (u & 0x80000000u) ? ~u : (u | 0x80000000u);
}

__global__ __launch_bounds__(NTHREADS) void histmin_kernel(
    const float* __restrict__ in, long long n,
    unsigned* __restrict__ hist, unsigned* __restrict__ minkey) {
    // 8 bin-interleaved histogram copies: index = bin*8 + (lane&7).
    // bank = (bin*8 + c) % 32 = 8*(bin%4) + c -> lanes sharing a bank are
    // those with equal lane%8 AND equal bin%4: expected ~2-way (free, m136).
    __shared__ unsigned h[NBINS * NC];
    for (int i = threadIdx.x; i < NBINS * NC; i += blockDim.x) h[i] = 0;
    __syncthreads();

    const unsigned c = threadIdx.x & (NC - 1);
    long long tid = (long long)blockIdx.x * blockDim.x + threadIdx.x;
    long long stride = (long long)gridDim.x * blockDim.x;
    const float4* in4 = (const float4*)in;
    long long n4 = n >> 2;

    float mn = 3.402823466e+38f;
    for (long long i = tid; i < n4; i += stride) {
        float4 v = in4[i];
        mn = fminf(mn, fminf(fminf(v.x, v.y), fminf(v.z, v.w)));
        unsigned ux = __float_as_uint(v.x) & 0x7FFFFFFFu;
        unsigned uy = __float_as_uint(v.y) & 0x7FFFFFFFu;
        unsigned uz = __float_as_uint(v.z) & 0x7FFFFFFFu;
        unsigned uw = __float_as_uint(v.w) & 0x7FFFFFFFu;
        atomicAdd(&h[(ux >> 20) * NC + c], 1u);
        atomicAdd(&h[(uy >> 20) * NC + c], 1u);
        atomicAdd(&h[(uz >> 20) * NC + c], 1u);
        atomicAdd(&h[(uw >> 20) * NC + c], 1u);
    }
    // tail (n not multiple of 4)
    for (long long i = (n4 << 2) + tid; i < n; i += stride) {
        float v = in[i];
        mn = fminf(mn, v);
        atomicAdd(&h[((__float_as_uint(v) & 0x7FFFFFFFu) >> 20) * NC + c], 1u);
    }
    __syncthreads();

    // flush histogram: sum the 8 copies per bin, one global atomic per bin
    for (int b = threadIdx.x; b < NBINS; b += blockDim.x) {
        unsigned s = 0;
#pragma unroll
        for (int j = 0; j < NC; ++j) s += h[b * NC + j];
        if (s) atomicAdd(&hist[b], s);
    }

    // block min reduce
    unsigned key = fkey(mn);
    for (int off = 32; off > 0; off >>= 1)
        key = min(key, (unsigned)__shfl_down((int)key, off));
    __shared__ unsigned wmin[NTHREADS / 64];
    if ((threadIdx.x & 63) == 0) wmin[threadIdx.x >> 6] = key;
    __syncthreads();
    if (threadIdx.x == 0) {
        unsigned m = wmin[0];
        for (int w = 1; w < (int)(blockDim.x >> 6); ++w) m = min(m, wmin[w]);
        atomicMin(minkey, m);
    }
}

__global__ void select_bucket_kernel(const unsigned* __restrict__ hist,
                                     unsigned k, unsigned* __restrict__ sel) {
    __shared__ unsigned part[256];
    int t = threadIdx.x;  // 256 threads
    unsigned s = 0;
    for (int j = 0; j < 8; ++j) s += hist[t * 8 + j];
    part[t] = s;
    __syncthreads();
    if (t == 0) {
        unsigned cum = 0;
        int seg = 0;
        for (; seg < 256; ++seg) {
            if (cum + part[seg] >= k) break;
            cum += part[seg];
        }
        int b = seg * 8;
        for (;; ++b) {
            unsigned c = hist[b];
            if (cum + c >= k) break;
            cum += c;
        }
        sel[0] = (unsigned)b;
        sel[1] = k - cum;  // 1-indexed rank within bucket
    }
}

__global__ __launch_bounds__(NTHREADS) void compact_kernel(
    const float* __restrict__ in, long long n,
    const unsigned* __restrict__ sel, unsigned* __restrict__ counter,
    unsigned* __restrict__ cand) {
    unsigned b = sel[0];
    long long tid = (long long)blockIdx.x * blockDim.x + threadIdx.x;
    long long stride = (long long)gridDim.x * blockDim.x;
    const float4* in4 = (const float4*)in;
    long long n4 = n >> 2;
    for (long long i = tid; i < n4; i += stride) {
        float4 v = in4[i];
        unsigned u[4];
        u[0] = __float_as_uint(v.x) & 0x7FFFFFFFu;
        u[1] = __float_as_uint(v.y) & 0x7FFFFFFFu;
        u[2] = __float_as_uint(v.z) & 0x7FFFFFFFu;
        u[3] = __float_as_uint(v.w) & 0x7FFFFFFFu;
#pragma unroll
        for (int j = 0; j < 4; ++j) {
            if ((u[j] >> 20) == b) {
                unsigned p = atomicAdd(counter, 1u);
                if (p < CAND_CAP) cand[p] = u[j];
            }
        }
    }
    for (long long i = (n4 << 2) + tid; i < n; i += stride) {
        unsigned u = __float_as_uint(in[i]) & 0x7FFFFFFFu;
        if ((u >> 20) == b) {
            unsigned p = atomicAdd(counter, 1u);
            if (p < CAND_CAP) cand[p] = u;
        }
    }
}

__global__ __launch_bounds__(1024) void final_kernel(
    const unsigned* __restrict__ cand, const unsigned* __restrict__ counterp,
    const unsigned* __restrict__ sel, const unsigned* __restrict__ minkeyp,
    const float* __restrict__ min_val, const float* __restrict__ max_val,
    const int* __restrict__ num_flag, float* __restrict__ out) {
    __shared__ unsigned h[1024];
    __shared__ unsigned part[32];
    __shared__ unsigned bsel[2];

    unsigned m = min(*counterp, (unsigned)CAND_CAP);
    unsigned b = sel[0];
    unsigned r = sel[1];

    // level 1: bits 19..10
    h[threadIdx.x] = 0;
    __syncthreads();
    for (unsigned i = threadIdx.x; i < m; i += blockDim.x)
        atomicAdd(&h[(cand[i] >> 10) & 1023u], 1u);
    __syncthreads();
    if (threadIdx.x < 32) {
        unsigned s = 0;
        for (int j = 0; j < 32; ++j) s += h[threadIdx.x * 32 + j];
        part[threadIdx.x] = s;
    }
    __syncthreads();
    if (threadIdx.x == 0) {
        unsigned cum = 0;
        int seg = 0;
        for (; seg < 32; ++seg) {
            if (cum + part[seg] >= r) break;
            cum += part[seg];
        }
        int i = seg * 32;
        for (;; ++i) {
            if (cum + h[i] >= r) break;
            cum += h[i];
        }
        bsel[0] = (unsigned)i;
        bsel[1] = r - cum;
    }
    __syncthreads();
    unsigned b1 = bsel[0];
    r = bsel[1];

    // level 2: bits 9..0
    h[threadIdx.x] = 0;
    __syncthreads();
    for (unsigned i = threadIdx.x; i < m; i += blockDim.x) {
        unsigned u = cand[i];
        if (((u >> 10) & 1023u) == b1) atomicAdd(&h[u & 1023u], 1u);
    }
    __syncthreads();
    if (threadIdx.x < 32) {
        unsigned s = 0;
        for (int j = 0; j < 32; ++j) s += h[threadIdx.x * 32 + j];
        part[threadIdx.x] = s;
    }
    __syncthreads();
    if (threadIdx.x == 0) {
        unsigned cum = 0;
        int seg = 0;
        for (; seg < 32; ++seg) {
            if (cum + part[seg] >= r) break;
            cum += part[seg];
        }
        int i = seg * 32;
        for (;; ++i) {
            if (cum + h[i] >= r) break;
            cum += h[i];
        }
        unsigned bits = (b << 20) | (b1 << 10) | (unsigned)i;
        float maxcur = __uint_as_float(bits);
        unsigned mk = *minkeyp;
        float mincur = (mk & 0x80000000u) ? __uint_as_float(mk & 0x7FFFFFFFu)
                                          : __uint_as_float(~mk);
        bool first = (*num_flag == 0);
        float nmax = first ? maxcur : (0.9f * max_val[0] + 0.1f * maxcur);
        float nmin = first ? mincur : (0.9f * min_val[0] + 0.1f * mincur);
        out[0] = nmin;
        out[1] = nmax;
    }
}

extern "C" void kernel_launch(void* const* d_in, const int* in_sizes, int n_in,
                              void* d_out, int out_size, void* d_ws, size_t ws_size,
                              hipStream_t stream) {
    const float* in = (const float*)d_in[0];
    const float* minv = (const float*)d_in[1];
    const float* maxv = (const float*)d_in[2];
    const int* flag = (const int*)d_in[3];
    float* out = (float*)d_out;

    long long n = (long long)in_sizes[0];
    // k = int(0.9999 * n), matching Python's double arithmetic + truncation
    unsigned k = (unsigned)(long long)(0.9999 * (double)n);

    unsigned* ws = (unsigned*)d_ws;
    unsigned* hist = ws;            // 2048
    unsigned* counter = ws + 2048;  // 1
    unsigned* minkey = ws + 2049;   // 1
    unsigned* sel = ws + 2050;      // 2
    unsigned* cand = ws + 2064;     // CAND_CAP

    hipMemsetAsync(ws, 0, 2064 * sizeof(unsigned), stream);
    hipMemsetAsync(minkey, 0xFF, sizeof(unsigned), stream);

    histmin_kernel<<<NBLOCKS, NTHREADS, 0, stream>>>(in, n, hist, minkey);
    select_bucket_kernel<<<1, 256, 0, stream>>>(hist, k, sel);
    compact_kernel<<<NBLOCKS, NTHREADS, 0, stream>>>(in, n, sel, counter, cand);
    final_kernel<<<1, 1024, 0, stream>>>(cand, counter, sel, minkey,
                                         minv, maxv, flag, out);
}